// Round 3
// baseline (183.043 us; speedup 1.0000x reference)
//
#include <hip/hip_runtime.h>

typedef unsigned short u16;
typedef short bf16x8 __attribute__((ext_vector_type(8)));
typedef float f32x4 __attribute__((ext_vector_type(4)));

#define DEVINL __device__ __forceinline__

// fp32 -> bf16 (round-to-nearest-even), bit-level
DEVINL u16 f2bf(float f) {
    union { float f; unsigned int u; } x;
    x.f = f;
    unsigned int u = x.u;
    unsigned int r = (u + 0x7fffu + ((u >> 16) & 1u)) >> 16;
    return (u16)r;
}

// async global->LDS, 16 bytes per lane. LDS dest must be wave-uniform base
// (HW adds lane*16); global src is per-lane.
DEVINL void async16(const u16* g, u16* l) {
    __builtin_amdgcn_global_load_lds(
        (const __attribute__((address_space(1))) void*)g,
        (__attribute__((address_space(3))) void*)l, 16, 0, 0);
}

// store helpers: bf16 intermediate vs fp32 final output
DEVINL void store_out(u16* p, float v)   { *p = f2bf(v); }
DEVINL void store_out(float* p, float v) { *p = v; }

// ---------------------------------------------------------------------------
// fp32 -> bf16 convert, vectorized (n4 = number of float4 groups)
// ---------------------------------------------------------------------------
__global__ void pma_cvt_kernel(const float* __restrict__ in, u16* __restrict__ out, int n4) {
    int i = blockIdx.x * blockDim.x + threadIdx.x;
    if (i < n4) {
        float4 v = reinterpret_cast<const float4*>(in)[i];
        ushort4 o;
        o.x = f2bf(v.x); o.y = f2bf(v.y); o.z = f2bf(v.z); o.w = f2bf(v.w);
        reinterpret_cast<ushort4*>(out)[i] = o;
    }
}

// ---------------------------------------------------------------------------
// GEMM: O[m][n] = sum_k A[m][k] * W[n][k]   (x @ W.T), all bf16, f32 acc.
// 128x128 tile, BK=32, 256 threads (4 waves, 2x2 of 64x64), m97 structure.
// Three W/O pointer pairs selected by blockIdx.y / nbn_per (QKV fusion).
// OutT = u16 (bf16 intermediates) or float (final d_out).
// ---------------------------------------------------------------------------
template <typename OutT>
__global__ __launch_bounds__(256) void pma_gemm_bt(
    const u16* __restrict__ A,
    const u16* __restrict__ W0, const u16* __restrict__ W1, const u16* __restrict__ W2,
    OutT* __restrict__ O0, OutT* __restrict__ O1, OutT* __restrict__ O2,
    int K, int nbn_per)
{
    const int t = threadIdx.x;
    const int lane = t & 63, wave = t >> 6;
    const int m0 = blockIdx.x * 128;
    const int bn = blockIdx.y;
    const int which = bn / nbn_per;
    const int n0 = (bn % nbn_per) * 128;
    const u16* W = (which == 0) ? W0 : (which == 1) ? W1 : W2;
    OutT* O = (which == 0) ? O0 : (which == 1) ? O1 : O2;

    __shared__ u16 Alds[128 * 32];
    __shared__ u16 Blds[128 * 32];

    const int wm = wave >> 1, wn = wave & 1;
    const int r16 = lane & 15, g4 = lane >> 4;

    f32x4 acc[4][4];
    const f32x4 z = {0.f, 0.f, 0.f, 0.f};
#pragma unroll
    for (int m = 0; m < 4; ++m)
#pragma unroll
        for (int n = 0; n < 4; ++n) acc[m][n] = z;

    for (int k0 = 0; k0 < K; k0 += 32) {
        __syncthreads();
#pragma unroll
        for (int j = 0; j < 2; ++j) {
            int i = j * 256 + t;
            int row = i >> 2, seg = i & 3;
            async16(A + (size_t)(m0 + row) * K + k0 + seg * 8,
                    Alds + (size_t)(j * 256 + wave * 64) * 8);
            async16(W + (size_t)(n0 + row) * K + k0 + seg * 8,
                    Blds + (size_t)(j * 256 + wave * 64) * 8);
        }
        __syncthreads();

        bf16x8 af[4], bfr[4];
#pragma unroll
        for (int m = 0; m < 4; ++m)
            af[m] = *reinterpret_cast<const bf16x8*>(Alds + (wm * 64 + m * 16 + r16) * 32 + g4 * 8);
#pragma unroll
        for (int n = 0; n < 4; ++n)
            bfr[n] = *reinterpret_cast<const bf16x8*>(Blds + (wn * 64 + n * 16 + r16) * 32 + g4 * 8);
#pragma unroll
        for (int m = 0; m < 4; ++m)
#pragma unroll
            for (int n = 0; n < 4; ++n)
                acc[m][n] = __builtin_amdgcn_mfma_f32_16x16x32_bf16(af[m], bfr[n], acc[m][n], 0, 0, 0);
    }

    // epilogue: C/D layout col = lane&15, row = (lane>>4)*4 + reg
#pragma unroll
    for (int m = 0; m < 4; ++m)
#pragma unroll
        for (int n = 0; n < 4; ++n) {
            int row = m0 + wm * 64 + m * 16 + g4 * 4;
            int col = n0 + wn * 64 + n * 16 + r16;
#pragma unroll
            for (int r = 0; r < 4; ++r)
                store_out(&O[(size_t)(row + r) * 1024 + col], acc[m][n][r]);
        }
}

// ---------------------------------------------------------------------------
// Flash attention (causal + padding), bf16 MFMA, fp32 accumulate.
// Layouts: Q/K/V/O all [B=2][S=2048][H=1024], head h occupies cols h*64..h*64+63.
// Block: 256 threads = 4 waves; block handles (b, h, 64 q-rows); wave -> 16 rows.
// Key tiles of 64, staged in LDS (K row-major padded, V transposed).
// ---------------------------------------------------------------------------
__global__ __launch_bounds__(256) void pma_attn_kernel(
    const u16* __restrict__ Q, const u16* __restrict__ Kp, const u16* __restrict__ Vp,
    const int* __restrict__ seq_lengths, u16* __restrict__ O)
{
    const int bx = blockIdx.x;
    const int qt = bx & 31;          // 32 q-tiles
    const int h  = (bx >> 5) & 15;   // 16 heads
    const int b  = bx >> 9;          // 2 batches
    const int q0 = qt * 64;
    const int t = threadIdx.x, lane = t & 63, w = t >> 6;
    const int r16 = lane & 15, g4 = lane >> 4;
    const int seqlen = seq_lengths[b];

    __shared__ u16 Klds[64 * 72];       // K rows (keys) x 64d (+8 pad)
    __shared__ u16 Vtlds[64 * 72];      // V transposed: d x keys (+8 pad)
    __shared__ u16 Plds[64 * 72];       // per-wave 16 rows x 64 keys (+8 pad)

    const size_t bbase = (size_t)b * 2048 * 1024;
    const size_t hoff = (size_t)h * 64;

    // Q fragments (A-operand): lane holds Q[q0+w*16+(l&15)][c*32 + (l>>4)*8 + j]
    const size_t qrowbase = bbase + (size_t)(q0 + w * 16 + r16) * 1024 + hoff;
    const bf16x8 qf0 = *reinterpret_cast<const bf16x8*>(Q + qrowbase + g4 * 8);
    const bf16x8 qf1 = *reinterpret_cast<const bf16x8*>(Q + qrowbase + 32 + g4 * 8);

    const f32x4 z = {0.f, 0.f, 0.f, 0.f};
    f32x4 acc[4];            // 4 d-chunks of 16; acc[f][r] row = (l>>4)*4+r
#pragma unroll
    for (int f = 0; f < 4; ++f) acc[f] = z;
    float mrow[4], lrow[4];
#pragma unroll
    for (int r = 0; r < 4; ++r) { mrow[r] = -1e30f; lrow[r] = 0.f; }

    int kmax = q0 + 63;
    if (seqlen - 1 < kmax) kmax = seqlen - 1;
    const int nt = (kmax >> 6) + 1;

    for (int tt = 0; tt < nt; ++tt) {
        const int t0 = tt << 6;
        // ---- stage K tile (row-major, padded) and V tile (transposed) ----
        // full tile = 64 rows x 64 cols = 512 chunks of 8; 256 threads x 2
#pragma unroll
        for (int j = 0; j < 2; ++j) {
            int idx = j * 256 + t;
            int row = idx >> 3, seg = idx & 7;
            const size_t gsrc = bbase + (size_t)(t0 + row) * 1024 + hoff + seg * 8;
            *reinterpret_cast<bf16x8*>(Klds + row * 72 + seg * 8) =
                *reinterpret_cast<const bf16x8*>(Kp + gsrc);
            bf16x8 vv = *reinterpret_cast<const bf16x8*>(Vp + gsrc);
#pragma unroll
            for (int jj = 0; jj < 8; ++jj)
                Vtlds[(seg * 8 + jj) * 72 + row] = (u16)vv[jj];
        }
        __syncthreads();

        // ---- scores: S[16 q x 64 k] via 8 MFMAs ----
        float sc[4][4];
#pragma unroll
        for (int kc = 0; kc < 4; ++kc) {
            bf16x8 kf0 = *reinterpret_cast<const bf16x8*>(Klds + (kc * 16 + r16) * 72 + g4 * 8);
            bf16x8 kf1 = *reinterpret_cast<const bf16x8*>(Klds + (kc * 16 + r16) * 72 + 32 + g4 * 8);
            f32x4 s = z;
            s = __builtin_amdgcn_mfma_f32_16x16x32_bf16(qf0, kf0, s, 0, 0, 0);
            s = __builtin_amdgcn_mfma_f32_16x16x32_bf16(qf1, kf1, s, 0, 0, 0);
            const int keyg = t0 + kc * 16 + r16;
#pragma unroll
            for (int r = 0; r < 4; ++r) {
                int qrow = q0 + w * 16 + g4 * 4 + r;
                float sv = s[r] * 0.125f;  // 1/sqrt(64)
                sc[kc][r] = ((keyg > qrow) || (keyg >= seqlen)) ? -1e30f : sv;
            }
        }

        // ---- online softmax ----
        float corr[4];
#pragma unroll
        for (int r = 0; r < 4; ++r) {
            float mx = fmaxf(fmaxf(sc[0][r], sc[1][r]), fmaxf(sc[2][r], sc[3][r]));
#pragma unroll
            for (int mk = 1; mk <= 8; mk <<= 1) mx = fmaxf(mx, __shfl_xor(mx, mk, 64));
            float mnew = fmaxf(mrow[r], mx);
            corr[r] = __expf(mrow[r] - mnew);
            float rs = 0.f;
#pragma unroll
            for (int kc = 0; kc < 4; ++kc) {
                float p = __expf(sc[kc][r] - mnew);
                sc[kc][r] = p;
                rs += p;
            }
#pragma unroll
            for (int mk = 1; mk <= 8; mk <<= 1) rs += __shfl_xor(rs, mk, 64);
            lrow[r] = lrow[r] * corr[r] + rs;
            mrow[r] = mnew;
            // write P (bf16) to this wave's private LDS region
#pragma unroll
            for (int kc = 0; kc < 4; ++kc)
                Plds[(w * 16 + g4 * 4 + r) * 72 + kc * 16 + r16] = f2bf(sc[kc][r]);
        }
#pragma unroll
        for (int f = 0; f < 4; ++f) {
            f32x4 a = acc[f];
            a[0] *= corr[0]; a[1] *= corr[1]; a[2] *= corr[2]; a[3] *= corr[3];
            acc[f] = a;
        }

        // ---- PV: out[16 x 64d] += P[16 x 64k] * V[64k x 64d] ----
#pragma unroll
        for (int kc2 = 0; kc2 < 2; ++kc2) {
            bf16x8 pa = *reinterpret_cast<const bf16x8*>(Plds + (w * 16 + r16) * 72 + kc2 * 32 + g4 * 8);
#pragma unroll
            for (int f = 0; f < 4; ++f) {
                bf16x8 vb = *reinterpret_cast<const bf16x8*>(Vtlds + (f * 16 + r16) * 72 + kc2 * 32 + g4 * 8);
                acc[f] = __builtin_amdgcn_mfma_f32_16x16x32_bf16(pa, vb, acc[f], 0, 0, 0);
            }
        }
        __syncthreads();
    }

    // ---- epilogue: normalize and store ----
#pragma unroll
    for (int f = 0; f < 4; ++f)
#pragma unroll
        for (int r = 0; r < 4; ++r) {
            int sr = q0 + w * 16 + g4 * 4 + r;
            float o = acc[f][r] / lrow[r];
            O[bbase + (size_t)sr * 1024 + hoff + f * 16 + r16] = f2bf(o);
        }
}

// ---------------------------------------------------------------------------
extern "C" void kernel_launch(void* const* d_in, const int* in_sizes, int n_in,
                              void* d_out, int out_size, void* d_ws, size_t ws_size,
                              hipStream_t stream) {
    const float* x   = (const float*)d_in[0];
    const int*   sql = (const int*)d_in[1];
    const float* Wq  = (const float*)d_in[2];
    const float* Wk  = (const float*)d_in[3];
    const float* Wv  = (const float*)d_in[4];
    const float* Wo  = (const float*)d_in[5];
    float* out = (float*)d_out;   // reference output dtype is float32

    const size_t MB = 1024 * 1024;
    char* ws = (char*)d_ws;
    u16* xb   = (u16*)(ws + 0 * MB);   // [4096][1024] bf16, 8 MB
    u16* wqb  = (u16*)(ws + 8 * MB);   // 2 MB each
    u16* wkb  = (u16*)(ws + 10 * MB);
    u16* wvb  = (u16*)(ws + 12 * MB);
    u16* wob  = (u16*)(ws + 14 * MB);
    u16* Qb   = (u16*)(ws + 16 * MB);  // 8 MB each
    u16* Kb   = (u16*)(ws + 24 * MB);
    u16* Vb   = (u16*)(ws + 32 * MB);
    u16* attb = (u16*)(ws + 40 * MB);  // total 48 MB

    // 1) convert inputs to bf16
    pma_cvt_kernel<<<4096, 256, 0, stream>>>(x,  xb,  1048576);  // 4096*1024/4
    pma_cvt_kernel<<<1024, 256, 0, stream>>>(Wq, wqb, 262144);   // 1024*1024/4
    pma_cvt_kernel<<<1024, 256, 0, stream>>>(Wk, wkb, 262144);
    pma_cvt_kernel<<<1024, 256, 0, stream>>>(Wv, wvb, 262144);
    pma_cvt_kernel<<<1024, 256, 0, stream>>>(Wo, wob, 262144);

    // 2) fused QKV projection: [4096,1024] x 3x[1024,1024]^T  (bf16 out)
    pma_gemm_bt<u16><<<dim3(32, 24), 256, 0, stream>>>(xb, wqb, wkb, wvb, Qb, Kb, Vb, 1024, 8);

    // 3) flash attention: 2 b * 16 h * 32 q-tiles = 1024 blocks
    pma_attn_kernel<<<1024, 256, 0, stream>>>(Qb, Kb, Vb, sql, attb);

    // 4) output projection -> d_out (fp32)
    pma_gemm_bt<float><<<dim3(32, 8), 256, 0, stream>>>(attb, wob, wob, wob, out, out, out, 1024, 8);
}

// Round 4
// 140.830 us; speedup vs baseline: 1.2997x; 1.2997x over previous
//
#include <hip/hip_runtime.h>

typedef unsigned short u16;
typedef short bf16x8 __attribute__((ext_vector_type(8)));
typedef float f32x4 __attribute__((ext_vector_type(4)));

#define DEVINL __device__ __forceinline__

// fp32 -> bf16 (round-to-nearest-even), bit-level
DEVINL u16 f2bf(float f) {
    union { float f; unsigned int u; } x;
    x.f = f;
    unsigned int u = x.u;
    unsigned int r = (u + 0x7fffu + ((u >> 16) & 1u)) >> 16;
    return (u16)r;
}

// async global->LDS, 16 bytes per lane. LDS dest must be wave-uniform base
// (HW adds lane*16); global src is per-lane.
DEVINL void async16(const u16* g, u16* l) {
    __builtin_amdgcn_global_load_lds(
        (const __attribute__((address_space(1))) void*)g,
        (__attribute__((address_space(3))) void*)l, 16, 0, 0);
}

// store helpers: bf16 intermediate vs fp32 final output
DEVINL void store_out(u16* p, float v)   { *p = f2bf(v); }
DEVINL void store_out(float* p, float v) { *p = v; }

// ---------------------------------------------------------------------------
// fp32 -> bf16 convert, vectorized (n4 = number of float4 groups)
// ---------------------------------------------------------------------------
__global__ void pma_cvt_kernel(const float* __restrict__ in, u16* __restrict__ out, int n4) {
    int i = blockIdx.x * blockDim.x + threadIdx.x;
    if (i < n4) {
        float4 v = reinterpret_cast<const float4*>(in)[i];
        ushort4 o;
        o.x = f2bf(v.x); o.y = f2bf(v.y); o.z = f2bf(v.z); o.w = f2bf(v.w);
        reinterpret_cast<ushort4*>(out)[i] = o;
    }
}

// ---------------------------------------------------------------------------
// GEMM: O[m][n] = sum_k A[m][k] * W[n][k]   (x @ W.T), all bf16, f32 acc.
// 128x128 tile, BK=32, 256 threads (4 waves, 2x2 of 64x64), m97 structure.
// ---------------------------------------------------------------------------
template <typename OutT>
__global__ __launch_bounds__(256) void pma_gemm_bt(
    const u16* __restrict__ A,
    const u16* __restrict__ W0, const u16* __restrict__ W1, const u16* __restrict__ W2,
    OutT* __restrict__ O0, OutT* __restrict__ O1, OutT* __restrict__ O2,
    int K, int nbn_per)
{
    const int t = threadIdx.x;
    const int lane = t & 63, wave = t >> 6;
    const int m0 = blockIdx.x * 128;
    const int bn = blockIdx.y;
    const int which = bn / nbn_per;
    const int n0 = (bn % nbn_per) * 128;
    const u16* W = (which == 0) ? W0 : (which == 1) ? W1 : W2;
    OutT* O = (which == 0) ? O0 : (which == 1) ? O1 : O2;

    __shared__ u16 Alds[128 * 32];
    __shared__ u16 Blds[128 * 32];

    const int wm = wave >> 1, wn = wave & 1;
    const int r16 = lane & 15, g4 = lane >> 4;

    f32x4 acc[4][4];
    const f32x4 z = {0.f, 0.f, 0.f, 0.f};
#pragma unroll
    for (int m = 0; m < 4; ++m)
#pragma unroll
        for (int n = 0; n < 4; ++n) acc[m][n] = z;

    for (int k0 = 0; k0 < K; k0 += 32) {
        __syncthreads();
#pragma unroll
        for (int j = 0; j < 2; ++j) {
            int i = j * 256 + t;
            int row = i >> 2, seg = i & 3;
            async16(A + (size_t)(m0 + row) * K + k0 + seg * 8,
                    Alds + (size_t)(j * 256 + wave * 64) * 8);
            async16(W + (size_t)(n0 + row) * K + k0 + seg * 8,
                    Blds + (size_t)(j * 256 + wave * 64) * 8);
        }
        __syncthreads();

        bf16x8 af[4], bfr[4];
#pragma unroll
        for (int m = 0; m < 4; ++m)
            af[m] = *reinterpret_cast<const bf16x8*>(Alds + (wm * 64 + m * 16 + r16) * 32 + g4 * 8);
#pragma unroll
        for (int n = 0; n < 4; ++n)
            bfr[n] = *reinterpret_cast<const bf16x8*>(Blds + (wn * 64 + n * 16 + r16) * 32 + g4 * 8);
#pragma unroll
        for (int m = 0; m < 4; ++m)
#pragma unroll
            for (int n = 0; n < 4; ++n)
                acc[m][n] = __builtin_amdgcn_mfma_f32_16x16x32_bf16(af[m], bfr[n], acc[m][n], 0, 0, 0);
    }

    // epilogue: C/D layout col = lane&15, row = (lane>>4)*4 + reg
#pragma unroll
    for (int m = 0; m < 4; ++m)
#pragma unroll
        for (int n = 0; n < 4; ++n) {
            int row = m0 + wm * 64 + m * 16 + g4 * 4;
            int col = n0 + wn * 64 + n * 16 + r16;
#pragma unroll
            for (int r = 0; r < 4; ++r)
                store_out(&O[(size_t)(row + r) * 1024 + col], acc[m][n][r]);
        }
}

// ---------------------------------------------------------------------------
// Flash attention (causal + padding), bf16 MFMA, fp32 accumulate.
// Swapped QK^T (mfma(K,Q)) => lane owns one q-row (q = lane&15), keys in-reg.
// V staged transposed with chunk-XOR-swizzled layout (conflict-free writes).
// T14 async staging: tile t+1 global loads issued before compute(t).
// ---------------------------------------------------------------------------
__global__ __launch_bounds__(256, 4) void pma_attn_kernel(
    const u16* __restrict__ Q, const u16* __restrict__ Kp, const u16* __restrict__ Vp,
    const int* __restrict__ seq_lengths, u16* __restrict__ O)
{
    const int bx = blockIdx.x;
    const int qt = bx & 31;          // 32 q-tiles
    const int h  = (bx >> 5) & 15;   // 16 heads
    const int b  = bx >> 9;          // 2 batches
    const int q0 = qt * 64;
    const int t = threadIdx.x, lane = t & 63, w = t >> 6;
    const int r16 = lane & 15, g4 = lane >> 4;
    const int seqlen = seq_lengths[b];

    __shared__ u16 Klds[64 * 72];    // keys x 64d, stride 72 (16B-aligned rows)
    __shared__ u16 Vtlds[64 * 72];   // d x keys, stride 72, chunk ^= (d>>3) swizzle
    __shared__ u16 Plds[64 * 68];    // q-rows x keys (stride 68)

    const size_t bbase = (size_t)b * 2048 * 1024;
    const size_t hoff = (size_t)h * 64;

    // Q B-fragment: lane r16 = q-row, k-dim = d
    const size_t qrowbase = bbase + (size_t)(q0 + w * 16 + r16) * 1024 + hoff;
    const bf16x8 qf0 = *reinterpret_cast<const bf16x8*>(Q + qrowbase + g4 * 8);
    const bf16x8 qf1 = *reinterpret_cast<const bf16x8*>(Q + qrowbase + 32 + g4 * 8);

    const f32x4 z = {0.f, 0.f, 0.f, 0.f};
    f32x4 acc[4];                    // 4 d-chunks; acc[f][r] -> row q0+w*16+g4*4+r, col f*16+r16
#pragma unroll
    for (int f = 0; f < 4; ++f) acc[f] = z;
    float mrow = -1e30f, lrow = 0.f; // per-lane state for q = r16 (dup across g4)

    int kmax = q0 + 63;
    if (seqlen - 1 < kmax) kmax = seqlen - 1;
    const int nt = (kmax >> 6) + 1;

    // staging geometry: idx = j*256 + t, krow = j*32 + w*8 + (lane>>3), seg = lane&7
    const int krel = t >> 3;         // 0..31 (within j half)
    const int seg  = t & 7;

    bf16x8 kreg[2], vreg[2];

    // ---- prologue: load + store tile 0 ----
#pragma unroll
    for (int j = 0; j < 2; ++j) {
        const size_t gsrc = bbase + (size_t)(j * 32 + krel) * 1024 + hoff + seg * 8;
        kreg[j] = *reinterpret_cast<const bf16x8*>(Kp + gsrc);
        vreg[j] = *reinterpret_cast<const bf16x8*>(Vp + gsrc);
    }
#pragma unroll
    for (int j = 0; j < 2; ++j) {
        const int k = j * 32 + krel;
        *reinterpret_cast<bf16x8*>(Klds + k * 72 + seg * 8) = kreg[j];
        const int kc3 = k >> 3, k7 = k & 7;
#pragma unroll
        for (int jj = 0; jj < 8; ++jj) {
            const int d = seg * 8 + jj;
            Vtlds[d * 72 + ((kc3 ^ (d >> 3)) << 3) + k7] = (u16)vreg[j][jj];
        }
    }
    __syncthreads();

    const int qhat = q0 + w * 16 + r16;

    for (int tt = 0; tt < nt; ++tt) {
        const int t0 = tt << 6;

        // ---- issue next tile's global loads (latency hides under compute) ----
        if (tt + 1 < nt) {
            const int t0n = (tt + 1) << 6;
#pragma unroll
            for (int j = 0; j < 2; ++j) {
                const size_t gsrc = bbase + (size_t)(t0n + j * 32 + krel) * 1024 + hoff + seg * 8;
                kreg[j] = *reinterpret_cast<const bf16x8*>(Kp + gsrc);
                vreg[j] = *reinterpret_cast<const bf16x8*>(Vp + gsrc);
            }
        }

        // ---- scores (swapped): S[key][q], lane holds 16 keys for q = r16 ----
        float sc[4][4];
#pragma unroll
        for (int kc = 0; kc < 4; ++kc) {
            bf16x8 kf0 = *reinterpret_cast<const bf16x8*>(Klds + (kc * 16 + r16) * 72 + g4 * 8);
            bf16x8 kf1 = *reinterpret_cast<const bf16x8*>(Klds + (kc * 16 + r16) * 72 + 32 + g4 * 8);
            f32x4 s = z;
            s = __builtin_amdgcn_mfma_f32_16x16x32_bf16(kf0, qf0, s, 0, 0, 0);
            s = __builtin_amdgcn_mfma_f32_16x16x32_bf16(kf1, qf1, s, 0, 0, 0);
            const int keyb = t0 + kc * 16 + g4 * 4;
#pragma unroll
            for (int r = 0; r < 4; ++r) {
                float sv = s[r] * 0.125f;  // 1/sqrt(64)
                sc[kc][r] = ((keyb + r > qhat) || (keyb + r >= seqlen)) ? -1e30f : sv;
            }
        }

        // ---- online softmax: in-lane over 16 keys, then 2 shfl over g4 ----
        float mx = sc[0][0];
#pragma unroll
        for (int kc = 0; kc < 4; ++kc)
#pragma unroll
            for (int r = 0; r < 4; ++r) mx = fmaxf(mx, sc[kc][r]);
        mx = fmaxf(mx, __shfl_xor(mx, 16, 64));
        mx = fmaxf(mx, __shfl_xor(mx, 32, 64));
        const float mnew = fmaxf(mrow, mx);
        const float corr = __expf(mrow - mnew);
        float rs = 0.f;
#pragma unroll
        for (int kc = 0; kc < 4; ++kc)
#pragma unroll
            for (int r = 0; r < 4; ++r) {
                float p = __expf(sc[kc][r] - mnew);
                sc[kc][r] = p;
                rs += p;
            }
        rs += __shfl_xor(rs, 16, 64);
        rs += __shfl_xor(rs, 32, 64);
        lrow = lrow * corr + rs;
        mrow = mnew;

        // ---- write P (bf16) as 4x b64: row q = w*16+r16, keys kc*16+g4*4.. ----
#pragma unroll
        for (int kc = 0; kc < 4; ++kc) {
            ushort4 pk;
            pk.x = f2bf(sc[kc][0]); pk.y = f2bf(sc[kc][1]);
            pk.z = f2bf(sc[kc][2]); pk.w = f2bf(sc[kc][3]);
            *reinterpret_cast<ushort4*>(Plds + (w * 16 + r16) * 68 + kc * 16 + g4 * 4) = pk;
        }

        // ---- rescale acc: corr for row g4*4+r lives in lane (g4*4+r) ----
        {
            float cr0 = __shfl(corr, g4 * 4 + 0, 64);
            float cr1 = __shfl(corr, g4 * 4 + 1, 64);
            float cr2 = __shfl(corr, g4 * 4 + 2, 64);
            float cr3 = __shfl(corr, g4 * 4 + 3, 64);
#pragma unroll
            for (int f = 0; f < 4; ++f) {
                f32x4 a = acc[f];
                a[0] *= cr0; a[1] *= cr1; a[2] *= cr2; a[3] *= cr3;
                acc[f] = a;
            }
        }

        // ---- PV: O[q][d] += P[q][k] * V[k][d] ----
#pragma unroll
        for (int kc2 = 0; kc2 < 2; ++kc2) {
            bf16x8 pa = *reinterpret_cast<const bf16x8*>(Plds + (w * 16 + r16) * 68 + kc2 * 32 + g4 * 8);
#pragma unroll
            for (int f = 0; f < 4; ++f) {
                const int d = f * 16 + r16;
                const int chunk = (kc2 * 4 + g4) ^ (d >> 3);
                bf16x8 vb = *reinterpret_cast<const bf16x8*>(Vtlds + d * 72 + (chunk << 3));
                acc[f] = __builtin_amdgcn_mfma_f32_16x16x32_bf16(pa, vb, acc[f], 0, 0, 0);
            }
        }
        __syncthreads();

        // ---- store next tile from regs (after all waves done reading) ----
        if (tt + 1 < nt) {
#pragma unroll
            for (int j = 0; j < 2; ++j) {
                const int k = j * 32 + krel;
                *reinterpret_cast<bf16x8*>(Klds + k * 72 + seg * 8) = kreg[j];
                const int kc3 = k >> 3, k7 = k & 7;
#pragma unroll
                for (int jj = 0; jj < 8; ++jj) {
                    const int d = seg * 8 + jj;
                    Vtlds[d * 72 + ((kc3 ^ (d >> 3)) << 3) + k7] = (u16)vreg[j][jj];
                }
            }
            __syncthreads();
        }
    }

    // ---- epilogue: normalize and store; lrow for row g4*4+r from lane g4*4+r ----
    {
        float lr0 = __shfl(lrow, g4 * 4 + 0, 64);
        float lr1 = __shfl(lrow, g4 * 4 + 1, 64);
        float lr2 = __shfl(lrow, g4 * 4 + 2, 64);
        float lr3 = __shfl(lrow, g4 * 4 + 3, 64);
        float lr[4] = {lr0, lr1, lr2, lr3};
#pragma unroll
        for (int f = 0; f < 4; ++f)
#pragma unroll
            for (int r = 0; r < 4; ++r) {
                int sr = q0 + w * 16 + g4 * 4 + r;
                float o = acc[f][r] / lr[r];
                O[bbase + (size_t)sr * 1024 + hoff + f * 16 + r16] = f2bf(o);
            }
    }
}

// ---------------------------------------------------------------------------
extern "C" void kernel_launch(void* const* d_in, const int* in_sizes, int n_in,
                              void* d_out, int out_size, void* d_ws, size_t ws_size,
                              hipStream_t stream) {
    const float* x   = (const float*)d_in[0];
    const int*   sql = (const int*)d_in[1];
    const float* Wq  = (const float*)d_in[2];
    const float* Wk  = (const float*)d_in[3];
    const float* Wv  = (const float*)d_in[4];
    const float* Wo  = (const float*)d_in[5];
    float* out = (float*)d_out;   // reference output dtype is float32

    const size_t MB = 1024 * 1024;
    char* ws = (char*)d_ws;
    u16* xb   = (u16*)(ws + 0 * MB);   // [4096][1024] bf16, 8 MB
    u16* wqb  = (u16*)(ws + 8 * MB);   // 2 MB each
    u16* wkb  = (u16*)(ws + 10 * MB);
    u16* wvb  = (u16*)(ws + 12 * MB);
    u16* wob  = (u16*)(ws + 14 * MB);
    u16* Qb   = (u16*)(ws + 16 * MB);  // 8 MB each
    u16* Kb   = (u16*)(ws + 24 * MB);
    u16* Vb   = (u16*)(ws + 32 * MB);
    u16* attb = (u16*)(ws + 40 * MB);  // total 48 MB

    // 1) convert inputs to bf16
    pma_cvt_kernel<<<4096, 256, 0, stream>>>(x,  xb,  1048576);
    pma_cvt_kernel<<<1024, 256, 0, stream>>>(Wq, wqb, 262144);
    pma_cvt_kernel<<<1024, 256, 0, stream>>>(Wk, wkb, 262144);
    pma_cvt_kernel<<<1024, 256, 0, stream>>>(Wv, wvb, 262144);
    pma_cvt_kernel<<<1024, 256, 0, stream>>>(Wo, wob, 262144);

    // 2) fused QKV projection: [4096,1024] x 3x[1024,1024]^T  (bf16 out)
    pma_gemm_bt<u16><<<dim3(32, 24), 256, 0, stream>>>(xb, wqb, wkb, wvb, Qb, Kb, Vb, 1024, 8);

    // 3) flash attention: 2 b * 16 h * 32 q-tiles = 1024 blocks
    pma_attn_kernel<<<1024, 256, 0, stream>>>(Qb, Kb, Vb, sql, attb);

    // 4) output projection -> d_out (fp32)
    pma_gemm_bt<float><<<dim3(32, 8), 256, 0, stream>>>(attb, wob, wob, wob, out, out, out, 1024, 8);
}

// Round 5
// 137.653 us; speedup vs baseline: 1.3297x; 1.0231x over previous
//
#include <hip/hip_runtime.h>

typedef unsigned short u16;
typedef short bf16x8 __attribute__((ext_vector_type(8)));
typedef float f32x4 __attribute__((ext_vector_type(4)));

#define DEVINL __device__ __forceinline__

// fp32 -> bf16 (round-to-nearest-even), bit-level
DEVINL u16 f2bf(float f) {
    union { float f; unsigned int u; } x;
    x.f = f;
    unsigned int u = x.u;
    unsigned int r = (u + 0x7fffu + ((u >> 16) & 1u)) >> 16;
    return (u16)r;
}

// async global->LDS, 16 bytes per lane. LDS dest must be wave-uniform base
// (HW adds lane*16); global src is per-lane.
DEVINL void async16(const u16* g, u16* l) {
    __builtin_amdgcn_global_load_lds(
        (const __attribute__((address_space(1))) void*)g,
        (__attribute__((address_space(3))) void*)l, 16, 0, 0);
}

// store helpers: bf16 intermediate vs fp32 final output
DEVINL void store_out(u16* p, float v)   { *p = f2bf(v); }
DEVINL void store_out(float* p, float v) { *p = v; }

// ---------------------------------------------------------------------------
// fp32 -> bf16 convert, vectorized (n4 = number of float4 groups)
// ---------------------------------------------------------------------------
__global__ void pma_cvt_kernel(const float* __restrict__ in, u16* __restrict__ out, int n4) {
    int i = blockIdx.x * blockDim.x + threadIdx.x;
    if (i < n4) {
        float4 v = reinterpret_cast<const float4*>(in)[i];
        ushort4 o;
        o.x = f2bf(v.x); o.y = f2bf(v.y); o.z = f2bf(v.z); o.w = f2bf(v.w);
        reinterpret_cast<ushort4*>(out)[i] = o;
    }
}

// 4 weight matrices (1024x1024 each) in one launch; outputs contiguous at dst.
__global__ void pma_cvt4_kernel(const float* __restrict__ w0, const float* __restrict__ w1,
                                const float* __restrict__ w2, const float* __restrict__ w3,
                                u16* __restrict__ dst) {
    const int wsel = blockIdx.y;
    const float* in = (wsel == 0) ? w0 : (wsel == 1) ? w1 : (wsel == 2) ? w2 : w3;
    u16* out = dst + (size_t)wsel * 1024 * 1024;
    int i = blockIdx.x * blockDim.x + threadIdx.x;   // 262144 float4 groups
    float4 v = reinterpret_cast<const float4*>(in)[i];
    ushort4 o;
    o.x = f2bf(v.x); o.y = f2bf(v.y); o.z = f2bf(v.z); o.w = f2bf(v.w);
    reinterpret_cast<ushort4*>(out)[i] = o;
}

// ---------------------------------------------------------------------------
// GEMM: O[m][n] = sum_k A[m][k] * W[n][k]   (x @ W.T), all bf16, f32 acc.
// 128x128 tile, BK=32, 256 threads (4 waves, 2x2 of 64x64), m97 structure.
// ---------------------------------------------------------------------------
template <typename OutT>
__global__ __launch_bounds__(256) void pma_gemm_bt(
    const u16* __restrict__ A,
    const u16* __restrict__ W0, const u16* __restrict__ W1, const u16* __restrict__ W2,
    OutT* __restrict__ O0, OutT* __restrict__ O1, OutT* __restrict__ O2,
    int K, int nbn_per)
{
    const int t = threadIdx.x;
    const int lane = t & 63, wave = t >> 6;
    const int m0 = blockIdx.x * 128;
    const int bn = blockIdx.y;
    const int which = bn / nbn_per;
    const int n0 = (bn % nbn_per) * 128;
    const u16* W = (which == 0) ? W0 : (which == 1) ? W1 : W2;
    OutT* O = (which == 0) ? O0 : (which == 1) ? O1 : O2;

    __shared__ u16 Alds[128 * 32];
    __shared__ u16 Blds[128 * 32];

    const int wm = wave >> 1, wn = wave & 1;
    const int r16 = lane & 15, g4 = lane >> 4;

    f32x4 acc[4][4];
    const f32x4 z = {0.f, 0.f, 0.f, 0.f};
#pragma unroll
    for (int m = 0; m < 4; ++m)
#pragma unroll
        for (int n = 0; n < 4; ++n) acc[m][n] = z;

    for (int k0 = 0; k0 < K; k0 += 32) {
        __syncthreads();
#pragma unroll
        for (int j = 0; j < 2; ++j) {
            int i = j * 256 + t;
            int row = i >> 2, seg = i & 3;
            async16(A + (size_t)(m0 + row) * K + k0 + seg * 8,
                    Alds + (size_t)(j * 256 + wave * 64) * 8);
            async16(W + (size_t)(n0 + row) * K + k0 + seg * 8,
                    Blds + (size_t)(j * 256 + wave * 64) * 8);
        }
        __syncthreads();

        bf16x8 af[4], bfr[4];
#pragma unroll
        for (int m = 0; m < 4; ++m)
            af[m] = *reinterpret_cast<const bf16x8*>(Alds + (wm * 64 + m * 16 + r16) * 32 + g4 * 8);
#pragma unroll
        for (int n = 0; n < 4; ++n)
            bfr[n] = *reinterpret_cast<const bf16x8*>(Blds + (wn * 64 + n * 16 + r16) * 32 + g4 * 8);
#pragma unroll
        for (int m = 0; m < 4; ++m)
#pragma unroll
            for (int n = 0; n < 4; ++n)
                acc[m][n] = __builtin_amdgcn_mfma_f32_16x16x32_bf16(af[m], bfr[n], acc[m][n], 0, 0, 0);
    }

    // epilogue: C/D layout col = lane&15, row = (lane>>4)*4 + reg
#pragma unroll
    for (int m = 0; m < 4; ++m)
#pragma unroll
        for (int n = 0; n < 4; ++n) {
            int row = m0 + wm * 64 + m * 16 + g4 * 4;
            int col = n0 + wn * 64 + n * 16 + r16;
#pragma unroll
            for (int r = 0; r < 4; ++r)
                store_out(&O[(size_t)(row + r) * 1024 + col], acc[m][n][r]);
        }
}

// ---------------------------------------------------------------------------
// Flash attention (causal + padding), bf16 MFMA, fp32 accumulate.
// Causal load balancing: block handles q-tile pair (p, 31-p) sequentially ->
// every block does ~33 tile-iterations (uniform). 512 blocks.
// Swapped QK^T (mfma(K,Q)): lane owns q-row r16, 16 keys in-register.
// V transposed + chunk-XOR swizzle; T14 async staging; setprio around MFMA.
// ---------------------------------------------------------------------------
__global__ __launch_bounds__(256, 4) void pma_attn_kernel(
    const u16* __restrict__ Q, const u16* __restrict__ Kp, const u16* __restrict__ Vp,
    const int* __restrict__ seq_lengths, u16* __restrict__ O)
{
    const int bx = blockIdx.x;
    const int p  = bx & 15;          // pair index -> q-tiles p and 31-p
    const int h  = (bx >> 4) & 15;   // 16 heads
    const int b  = bx >> 8;          // 2 batches
    const int t = threadIdx.x, lane = t & 63, w = t >> 6;
    const int r16 = lane & 15, g4 = lane >> 4;
    const int seqlen = seq_lengths[b];

    __shared__ u16 Klds[64 * 72];    // keys x 64d, stride 72 (16B-aligned rows)
    __shared__ u16 Vtlds[64 * 72];   // d x keys, stride 72, chunk ^= (d>>3) swizzle
    __shared__ u16 Plds[64 * 72];    // q-rows x keys, stride 72 (16B-aligned rows)

    const size_t bbase = (size_t)b * 2048 * 1024;
    const size_t hoff = (size_t)h * 64;

    const f32x4 z = {0.f, 0.f, 0.f, 0.f};

    // staging geometry: krow = j*32 + (t>>3), seg = t&7
    const int krel = t >> 3;
    const int seg  = t & 7;

    for (int half = 0; half < 2; ++half) {
        const int qt = half ? (31 - p) : p;
        const int q0 = qt * 64;

        // Q B-fragment: lane r16 = q-row, k-dim = d
        const size_t qrowbase = bbase + (size_t)(q0 + w * 16 + r16) * 1024 + hoff;
        const bf16x8 qf0 = *reinterpret_cast<const bf16x8*>(Q + qrowbase + g4 * 8);
        const bf16x8 qf1 = *reinterpret_cast<const bf16x8*>(Q + qrowbase + 32 + g4 * 8);

        f32x4 acc[4];
#pragma unroll
        for (int f = 0; f < 4; ++f) acc[f] = z;
        float mrow = -1e30f, lrow = 0.f;

        int kmax = q0 + 63;
        if (seqlen - 1 < kmax) kmax = seqlen - 1;
        const int nt = (kmax >> 6) + 1;

        bf16x8 kreg[2], vreg[2];

        // ---- prologue: load + store tile 0 ----
#pragma unroll
        for (int j = 0; j < 2; ++j) {
            const size_t gsrc = bbase + (size_t)(j * 32 + krel) * 1024 + hoff + seg * 8;
            kreg[j] = *reinterpret_cast<const bf16x8*>(Kp + gsrc);
            vreg[j] = *reinterpret_cast<const bf16x8*>(Vp + gsrc);
        }
#pragma unroll
        for (int j = 0; j < 2; ++j) {
            const int k = j * 32 + krel;
            *reinterpret_cast<bf16x8*>(Klds + k * 72 + seg * 8) = kreg[j];
            const int kc3 = k >> 3, k7 = k & 7;
#pragma unroll
            for (int jj = 0; jj < 8; ++jj) {
                const int d = seg * 8 + jj;
                Vtlds[d * 72 + ((kc3 ^ (d >> 3)) << 3) + k7] = (u16)vreg[j][jj];
            }
        }
        __syncthreads();

        const int qhat = q0 + w * 16 + r16;

        for (int tt = 0; tt < nt; ++tt) {
            const int t0 = tt << 6;

            // ---- issue next tile's global loads (hide under compute) ----
            if (tt + 1 < nt) {
                const int t0n = (tt + 1) << 6;
#pragma unroll
                for (int j = 0; j < 2; ++j) {
                    const size_t gsrc = bbase + (size_t)(t0n + j * 32 + krel) * 1024 + hoff + seg * 8;
                    kreg[j] = *reinterpret_cast<const bf16x8*>(Kp + gsrc);
                    vreg[j] = *reinterpret_cast<const bf16x8*>(Vp + gsrc);
                }
            }

            // ---- scores (swapped): lane holds 16 keys for q = r16 ----
            float sc[4][4];
            __builtin_amdgcn_s_setprio(1);
#pragma unroll
            for (int kc = 0; kc < 4; ++kc) {
                bf16x8 kf0 = *reinterpret_cast<const bf16x8*>(Klds + (kc * 16 + r16) * 72 + g4 * 8);
                bf16x8 kf1 = *reinterpret_cast<const bf16x8*>(Klds + (kc * 16 + r16) * 72 + 32 + g4 * 8);
                f32x4 s = z;
                s = __builtin_amdgcn_mfma_f32_16x16x32_bf16(kf0, qf0, s, 0, 0, 0);
                s = __builtin_amdgcn_mfma_f32_16x16x32_bf16(kf1, qf1, s, 0, 0, 0);
                const int keyb = t0 + kc * 16 + g4 * 4;
#pragma unroll
                for (int r = 0; r < 4; ++r) {
                    float sv = s[r] * 0.125f;  // 1/sqrt(64)
                    sc[kc][r] = ((keyb + r > qhat) || (keyb + r >= seqlen)) ? -1e30f : sv;
                }
            }
            __builtin_amdgcn_s_setprio(0);

            // ---- online softmax: tree reduce in-lane, 2 shfl across g4 ----
            float mx;
            {
                float m0 = fmaxf(fmaxf(sc[0][0], sc[0][1]), fmaxf(sc[0][2], sc[0][3]));
                float m1 = fmaxf(fmaxf(sc[1][0], sc[1][1]), fmaxf(sc[1][2], sc[1][3]));
                float m2 = fmaxf(fmaxf(sc[2][0], sc[2][1]), fmaxf(sc[2][2], sc[2][3]));
                float m3 = fmaxf(fmaxf(sc[3][0], sc[3][1]), fmaxf(sc[3][2], sc[3][3]));
                mx = fmaxf(fmaxf(m0, m1), fmaxf(m2, m3));
            }
            mx = fmaxf(mx, __shfl_xor(mx, 16, 64));
            mx = fmaxf(mx, __shfl_xor(mx, 32, 64));
            const float mnew = fmaxf(mrow, mx);
            const float corr = __expf(mrow - mnew);
#pragma unroll
            for (int kc = 0; kc < 4; ++kc)
#pragma unroll
                for (int r = 0; r < 4; ++r)
                    sc[kc][r] = __expf(sc[kc][r] - mnew);
            float rs;
            {
                float s0 = (sc[0][0] + sc[0][1]) + (sc[0][2] + sc[0][3]);
                float s1 = (sc[1][0] + sc[1][1]) + (sc[1][2] + sc[1][3]);
                float s2 = (sc[2][0] + sc[2][1]) + (sc[2][2] + sc[2][3]);
                float s3 = (sc[3][0] + sc[3][1]) + (sc[3][2] + sc[3][3]);
                rs = (s0 + s1) + (s2 + s3);
            }
            rs += __shfl_xor(rs, 16, 64);
            rs += __shfl_xor(rs, 32, 64);
            lrow = lrow * corr + rs;
            mrow = mnew;

            // ---- write P (bf16) 4x b64: row w*16+r16, keys kc*16+g4*4 ----
#pragma unroll
            for (int kc = 0; kc < 4; ++kc) {
                ushort4 pk;
                pk.x = f2bf(sc[kc][0]); pk.y = f2bf(sc[kc][1]);
                pk.z = f2bf(sc[kc][2]); pk.w = f2bf(sc[kc][3]);
                *reinterpret_cast<ushort4*>(Plds + (w * 16 + r16) * 72 + kc * 16 + g4 * 4) = pk;
            }

            // ---- rescale acc: corr for row g4*4+r lives in lane g4*4+r ----
            {
                float cr0 = __shfl(corr, g4 * 4 + 0, 64);
                float cr1 = __shfl(corr, g4 * 4 + 1, 64);
                float cr2 = __shfl(corr, g4 * 4 + 2, 64);
                float cr3 = __shfl(corr, g4 * 4 + 3, 64);
#pragma unroll
                for (int f = 0; f < 4; ++f) {
                    f32x4 a = acc[f];
                    a[0] *= cr0; a[1] *= cr1; a[2] *= cr2; a[3] *= cr3;
                    acc[f] = a;
                }
            }

            // ---- PV: O[q][d] += P[q][k] * V[k][d] ----
            __builtin_amdgcn_s_setprio(1);
#pragma unroll
            for (int kc2 = 0; kc2 < 2; ++kc2) {
                bf16x8 pa = *reinterpret_cast<const bf16x8*>(Plds + (w * 16 + r16) * 72 + kc2 * 32 + g4 * 8);
#pragma unroll
                for (int f = 0; f < 4; ++f) {
                    const int d = f * 16 + r16;
                    const int chunk = (kc2 * 4 + g4) ^ (d >> 3);
                    bf16x8 vb = *reinterpret_cast<const bf16x8*>(Vtlds + d * 72 + (chunk << 3));
                    acc[f] = __builtin_amdgcn_mfma_f32_16x16x32_bf16(pa, vb, acc[f], 0, 0, 0);
                }
            }
            __builtin_amdgcn_s_setprio(0);
            __syncthreads();

            // ---- store next tile from regs (after all waves done reading) ----
            if (tt + 1 < nt) {
#pragma unroll
                for (int j = 0; j < 2; ++j) {
                    const int k = j * 32 + krel;
                    *reinterpret_cast<bf16x8*>(Klds + k * 72 + seg * 8) = kreg[j];
                    const int kc3 = k >> 3, k7 = k & 7;
#pragma unroll
                    for (int jj = 0; jj < 8; ++jj) {
                        const int d = seg * 8 + jj;
                        Vtlds[d * 72 + ((kc3 ^ (d >> 3)) << 3) + k7] = (u16)vreg[j][jj];
                    }
                }
                __syncthreads();
            }
        }

        // ---- epilogue: normalize and store ----
        {
            float lr0 = __shfl(lrow, g4 * 4 + 0, 64);
            float lr1 = __shfl(lrow, g4 * 4 + 1, 64);
            float lr2 = __shfl(lrow, g4 * 4 + 2, 64);
            float lr3 = __shfl(lrow, g4 * 4 + 3, 64);
            float lr[4] = {lr0, lr1, lr2, lr3};
#pragma unroll
            for (int f = 0; f < 4; ++f)
#pragma unroll
                for (int r = 0; r < 4; ++r) {
                    int sr = q0 + w * 16 + g4 * 4 + r;
                    float o = acc[f][r] / lr[r];
                    O[bbase + (size_t)sr * 1024 + hoff + f * 16 + r16] = f2bf(o);
                }
        }
    }
}

// ---------------------------------------------------------------------------
extern "C" void kernel_launch(void* const* d_in, const int* in_sizes, int n_in,
                              void* d_out, int out_size, void* d_ws, size_t ws_size,
                              hipStream_t stream) {
    const float* x   = (const float*)d_in[0];
    const int*   sql = (const int*)d_in[1];
    const float* Wq  = (const float*)d_in[2];
    const float* Wk  = (const float*)d_in[3];
    const float* Wv  = (const float*)d_in[4];
    const float* Wo  = (const float*)d_in[5];
    float* out = (float*)d_out;   // reference output dtype is float32

    const size_t MB = 1024 * 1024;
    char* ws = (char*)d_ws;
    u16* xb   = (u16*)(ws + 0 * MB);   // [4096][1024] bf16, 8 MB
    u16* wqb  = (u16*)(ws + 8 * MB);   // 2 MB each, contiguous wq,wk,wv,wo
    u16* wkb  = (u16*)(ws + 10 * MB);
    u16* wvb  = (u16*)(ws + 12 * MB);
    u16* wob  = (u16*)(ws + 14 * MB);
    u16* Qb   = (u16*)(ws + 16 * MB);  // 8 MB each
    u16* Kb   = (u16*)(ws + 24 * MB);
    u16* Vb   = (u16*)(ws + 32 * MB);
    u16* attb = (u16*)(ws + 40 * MB);  // total 48 MB

    // 1) convert inputs to bf16 (x + all 4 weights in 2 launches)
    pma_cvt_kernel<<<4096, 256, 0, stream>>>(x, xb, 1048576);
    pma_cvt4_kernel<<<dim3(1024, 4), 256, 0, stream>>>(Wq, Wk, Wv, Wo, wqb);

    // 2) fused QKV projection: [4096,1024] x 3x[1024,1024]^T  (bf16 out)
    pma_gemm_bt<u16><<<dim3(32, 24), 256, 0, stream>>>(xb, wqb, wkb, wvb, Qb, Kb, Vb, 1024, 8);

    // 3) flash attention: 2 b * 16 h * 16 pairs = 512 blocks (balanced)
    pma_attn_kernel<<<512, 256, 0, stream>>>(Qb, Kb, Vb, sql, attb);

    // 4) output projection -> d_out (fp32)
    pma_gemm_bt<float><<<dim3(32, 8), 256, 0, stream>>>(attb, wob, wob, wob, out, out, out, 1024, 8);
}

// Round 6
// 132.516 us; speedup vs baseline: 1.3813x; 1.0388x over previous
//
#include <hip/hip_runtime.h>

typedef unsigned short u16;
typedef short bf16x8 __attribute__((ext_vector_type(8)));
typedef float f32x4 __attribute__((ext_vector_type(4)));

#define DEVINL __device__ __forceinline__

// fp32 -> bf16 (round-to-nearest-even), bit-level
DEVINL u16 f2bf(float f) {
    union { float f; unsigned int u; } x;
    x.f = f;
    unsigned int u = x.u;
    unsigned int r = (u + 0x7fffu + ((u >> 16) & 1u)) >> 16;
    return (u16)r;
}

// fast fp32 -> bf16 (round-half-up); used for P in [0,1] only
DEVINL u16 f2bf_fast(float f) {
    union { float f; unsigned int u; } x;
    x.f = f;
    return (u16)((x.u + 0x8000u) >> 16);
}

// async global->LDS, 16 bytes per lane.
DEVINL void async16(const u16* g, u16* l) {
    __builtin_amdgcn_global_load_lds(
        (const __attribute__((address_space(1))) void*)g,
        (__attribute__((address_space(3))) void*)l, 16, 0, 0);
}

// store helpers: bf16 intermediate vs fp32 final output
DEVINL void store_out(u16* p, float v)   { *p = f2bf(v); }
DEVINL void store_out(float* p, float v) { *p = v; }

// ---------------------------------------------------------------------------
// fp32 -> bf16 convert, vectorized
// ---------------------------------------------------------------------------
__global__ void pma_cvt_kernel(const float* __restrict__ in, u16* __restrict__ out, int n4) {
    int i = blockIdx.x * blockDim.x + threadIdx.x;
    if (i < n4) {
        float4 v = reinterpret_cast<const float4*>(in)[i];
        ushort4 o;
        o.x = f2bf(v.x); o.y = f2bf(v.y); o.z = f2bf(v.z); o.w = f2bf(v.w);
        reinterpret_cast<ushort4*>(out)[i] = o;
    }
}

// 4 weight matrices in one launch; Wq (wsel==0) pre-scaled by 1/8 (= 1/sqrt(64), exact).
__global__ void pma_cvt4_kernel(const float* __restrict__ w0, const float* __restrict__ w1,
                                const float* __restrict__ w2, const float* __restrict__ w3,
                                u16* __restrict__ dst) {
    const int wsel = blockIdx.y;
    const float* in = (wsel == 0) ? w0 : (wsel == 1) ? w1 : (wsel == 2) ? w2 : w3;
    u16* out = dst + (size_t)wsel * 1024 * 1024;
    const float s = (wsel == 0) ? 0.125f : 1.0f;
    int i = blockIdx.x * blockDim.x + threadIdx.x;
    float4 v = reinterpret_cast<const float4*>(in)[i];
    ushort4 o;
    o.x = f2bf(v.x * s); o.y = f2bf(v.y * s); o.z = f2bf(v.z * s); o.w = f2bf(v.w * s);
    reinterpret_cast<ushort4*>(out)[i] = o;
}

// ---------------------------------------------------------------------------
// GEMM: O[m][n] = sum_k A[m][k] * W[n][k], bf16 in, f32 acc, 128x128 tile.
// which == vtr_which (bf16 out only): store transposed into [bh*64+d][2048 s]
// layout (V for attention). Otherwise row-major [row][1024].
// ---------------------------------------------------------------------------
template <typename OutT>
__global__ __launch_bounds__(256) void pma_gemm_bt(
    const u16* __restrict__ A,
    const u16* __restrict__ W0, const u16* __restrict__ W1, const u16* __restrict__ W2,
    OutT* __restrict__ O0, OutT* __restrict__ O1, OutT* __restrict__ O2,
    int K, int nbn_per, int vtr_which)
{
    const int t = threadIdx.x;
    const int lane = t & 63, wave = t >> 6;
    const int m0 = blockIdx.x * 128;
    const int bn = blockIdx.y;
    const int which = bn / nbn_per;
    const int n0 = (bn % nbn_per) * 128;
    const u16* W = (which == 0) ? W0 : (which == 1) ? W1 : W2;
    OutT* O = (which == 0) ? O0 : (which == 1) ? O1 : O2;

    __shared__ u16 Alds[128 * 32];
    __shared__ u16 Blds[128 * 32];

    const int wm = wave >> 1, wn = wave & 1;
    const int r16 = lane & 15, g4 = lane >> 4;

    f32x4 acc[4][4];
    const f32x4 z = {0.f, 0.f, 0.f, 0.f};
#pragma unroll
    for (int m = 0; m < 4; ++m)
#pragma unroll
        for (int n = 0; n < 4; ++n) acc[m][n] = z;

    for (int k0 = 0; k0 < K; k0 += 32) {
        __syncthreads();
#pragma unroll
        for (int j = 0; j < 2; ++j) {
            int i = j * 256 + t;
            int row = i >> 2, seg = i & 3;
            async16(A + (size_t)(m0 + row) * K + k0 + seg * 8,
                    Alds + (size_t)(j * 256 + wave * 64) * 8);
            async16(W + (size_t)(n0 + row) * K + k0 + seg * 8,
                    Blds + (size_t)(j * 256 + wave * 64) * 8);
        }
        __syncthreads();

        bf16x8 af[4], bfr[4];
#pragma unroll
        for (int m = 0; m < 4; ++m)
            af[m] = *reinterpret_cast<const bf16x8*>(Alds + (wm * 64 + m * 16 + r16) * 32 + g4 * 8);
#pragma unroll
        for (int n = 0; n < 4; ++n)
            bfr[n] = *reinterpret_cast<const bf16x8*>(Blds + (wn * 64 + n * 16 + r16) * 32 + g4 * 8);
#pragma unroll
        for (int m = 0; m < 4; ++m)
#pragma unroll
            for (int n = 0; n < 4; ++n)
                acc[m][n] = __builtin_amdgcn_mfma_f32_16x16x32_bf16(af[m], bfr[n], acc[m][n], 0, 0, 0);
    }

    // epilogue: C/D layout col = lane&15, row = (lane>>4)*4 + reg
    bool vtr = false;
    if constexpr (sizeof(OutT) == 2) vtr = (which == vtr_which);
    if (vtr) {
        if constexpr (sizeof(OutT) == 2) {
            // transposed store: Vt[((row>>11)*16 + col>>6)*64 + (col&63)][row&2047]
#pragma unroll
            for (int m = 0; m < 4; ++m)
#pragma unroll
                for (int n = 0; n < 4; ++n) {
                    int row = m0 + wm * 64 + m * 16 + g4 * 4;
                    int col = n0 + wn * 64 + n * 16 + r16;
                    ushort4 pk;
                    pk.x = f2bf(acc[m][n][0]); pk.y = f2bf(acc[m][n][1]);
                    pk.z = f2bf(acc[m][n][2]); pk.w = f2bf(acc[m][n][3]);
                    size_t addr = ((size_t)((row >> 11) * 16 + (col >> 6)) * 64 + (col & 63)) * 2048
                                  + (row & 2047);
                    *reinterpret_cast<ushort4*>((u16*)O + addr) = pk;
                }
        }
    } else {
#pragma unroll
        for (int m = 0; m < 4; ++m)
#pragma unroll
            for (int n = 0; n < 4; ++n) {
                int row = m0 + wm * 64 + m * 16 + g4 * 4;
                int col = n0 + wn * 64 + n * 16 + r16;
#pragma unroll
                for (int r = 0; r < 4; ++r)
                    store_out(&O[(size_t)(row + r) * 1024 + col], acc[m][n][r]);
            }
    }
}

// ---------------------------------------------------------------------------
// Flash attention (causal + padding), bf16 MFMA, fp32 accumulate.
// - block = q-tile pair (p, 31-p), 4 waves, 16 q-rows/wave
// - swapped QK^T: lane owns q-row r16, 16 keys in-register
// - V pre-transposed in global ([bh*64+d][s]) -> LDS staging identical to K
// - mask code only on diagonal / seqlen-boundary tiles
// - Wq pre-scaled by 1/8; softmax in exp2 domain
// ---------------------------------------------------------------------------
__global__ __launch_bounds__(256, 4) void pma_attn_kernel(
    const u16* __restrict__ Q, const u16* __restrict__ Kp, const u16* __restrict__ Vt,
    const int* __restrict__ seq_lengths, u16* __restrict__ O)
{
    const int bx = blockIdx.x;
    const int p  = bx & 15;          // pair index -> q-tiles p and 31-p
    const int h  = (bx >> 4) & 15;
    const int b  = bx >> 8;
    const int t = threadIdx.x, lane = t & 63, w = t >> 6;
    const int r16 = lane & 15, g4 = lane >> 4;
    const int seqlen = seq_lengths[b];
    const float L2E = 1.4426950408889634f;

    __shared__ u16 Klds[64 * 72];    // keys x 64d, stride 72
    __shared__ u16 Vtlds[64 * 72];   // d x keys, stride 72 (no swizzle needed)
    __shared__ u16 Plds[64 * 72];    // q-rows x keys, stride 72

    const size_t bbase = (size_t)b * 2048 * 1024;
    const size_t hoff = (size_t)h * 64;
    const size_t vrow0 = (size_t)((b * 16 + h) * 64);   // Vt row base for this (b,h)

    const f32x4 z = {0.f, 0.f, 0.f, 0.f};
    const int krel = t >> 3;         // 0..31
    const int seg  = t & 7;

    for (int half = 0; half < 2; ++half) {
        const int qt = half ? (31 - p) : p;
        const int q0 = qt * 64;

        const size_t qrowbase = bbase + (size_t)(q0 + w * 16 + r16) * 1024 + hoff;
        const bf16x8 qf0 = *reinterpret_cast<const bf16x8*>(Q + qrowbase + g4 * 8);
        const bf16x8 qf1 = *reinterpret_cast<const bf16x8*>(Q + qrowbase + 32 + g4 * 8);

        f32x4 acc[4];
#pragma unroll
        for (int f = 0; f < 4; ++f) acc[f] = z;
        float mrow = -1e30f, lrow = 0.f;

        int kmax = q0 + 63;
        if (seqlen - 1 < kmax) kmax = seqlen - 1;
        const int nt = (kmax >> 6) + 1;

        bf16x8 kreg[2], vreg[2];

        // ---- prologue: load + store tile 0 ----
#pragma unroll
        for (int j = 0; j < 2; ++j) {
            const int rr = j * 32 + krel;
            kreg[j] = *reinterpret_cast<const bf16x8*>(Kp + bbase + (size_t)rr * 1024 + hoff + seg * 8);
            vreg[j] = *reinterpret_cast<const bf16x8*>(Vt + (vrow0 + rr) * 2048 + seg * 8);
        }
#pragma unroll
        for (int j = 0; j < 2; ++j) {
            const int rr = j * 32 + krel;
            *reinterpret_cast<bf16x8*>(Klds + rr * 72 + seg * 8) = kreg[j];
            *reinterpret_cast<bf16x8*>(Vtlds + rr * 72 + seg * 8) = vreg[j];
        }
        __syncthreads();

        const int qhat = q0 + w * 16 + r16;

        for (int tt = 0; tt < nt; ++tt) {
            const int t0 = tt << 6;

            // ---- issue next tile's global loads (hide under compute) ----
            if (tt + 1 < nt) {
                const int t0n = (tt + 1) << 6;
#pragma unroll
                for (int j = 0; j < 2; ++j) {
                    const int rr = j * 32 + krel;
                    kreg[j] = *reinterpret_cast<const bf16x8*>(Kp + bbase + (size_t)(t0n + rr) * 1024 + hoff + seg * 8);
                    vreg[j] = *reinterpret_cast<const bf16x8*>(Vt + (vrow0 + rr) * 2048 + t0n + seg * 8);
                }
            }

            // ---- scores (swapped): lane holds 16 keys for q = r16 ----
            f32x4 sraw[4];
            __builtin_amdgcn_s_setprio(1);
#pragma unroll
            for (int kc = 0; kc < 4; ++kc) {
                bf16x8 kf0 = *reinterpret_cast<const bf16x8*>(Klds + (kc * 16 + r16) * 72 + g4 * 8);
                bf16x8 kf1 = *reinterpret_cast<const bf16x8*>(Klds + (kc * 16 + r16) * 72 + 32 + g4 * 8);
                f32x4 s = z;
                s = __builtin_amdgcn_mfma_f32_16x16x32_bf16(kf0, qf0, s, 0, 0, 0);
                s = __builtin_amdgcn_mfma_f32_16x16x32_bf16(kf1, qf1, s, 0, 0, 0);
                sraw[kc] = s;
            }
            __builtin_amdgcn_s_setprio(0);

            float sc[4][4];
            const bool needmask = (t0 == q0) || (t0 + 64 > seqlen);
            if (needmask) {
#pragma unroll
                for (int kc = 0; kc < 4; ++kc) {
                    const int keyb = t0 + kc * 16 + g4 * 4;
#pragma unroll
                    for (int r = 0; r < 4; ++r)
                        sc[kc][r] = ((keyb + r > qhat) || (keyb + r >= seqlen)) ? -1e30f : sraw[kc][r];
                }
            } else {
#pragma unroll
                for (int kc = 0; kc < 4; ++kc)
#pragma unroll
                    for (int r = 0; r < 4; ++r) sc[kc][r] = sraw[kc][r];
            }

            // ---- online softmax (exp2 domain) ----
            float mx;
            {
                float m0 = fmaxf(fmaxf(sc[0][0], sc[0][1]), fmaxf(sc[0][2], sc[0][3]));
                float m1 = fmaxf(fmaxf(sc[1][0], sc[1][1]), fmaxf(sc[1][2], sc[1][3]));
                float m2 = fmaxf(fmaxf(sc[2][0], sc[2][1]), fmaxf(sc[2][2], sc[2][3]));
                float m3 = fmaxf(fmaxf(sc[3][0], sc[3][1]), fmaxf(sc[3][2], sc[3][3]));
                mx = fmaxf(fmaxf(m0, m1), fmaxf(m2, m3));
            }
            mx = fmaxf(mx, __shfl_xor(mx, 16, 64));
            mx = fmaxf(mx, __shfl_xor(mx, 32, 64));
            const float mnew = fmaxf(mrow, mx);
            const float corr = exp2f((mrow - mnew) * L2E);
            const float nb = mnew * L2E;
#pragma unroll
            for (int kc = 0; kc < 4; ++kc)
#pragma unroll
                for (int r = 0; r < 4; ++r)
                    sc[kc][r] = exp2f(__builtin_fmaf(sc[kc][r], L2E, -nb));
            float rs;
            {
                float s0 = (sc[0][0] + sc[0][1]) + (sc[0][2] + sc[0][3]);
                float s1 = (sc[1][0] + sc[1][1]) + (sc[1][2] + sc[1][3]);
                float s2 = (sc[2][0] + sc[2][1]) + (sc[2][2] + sc[2][3]);
                float s3 = (sc[3][0] + sc[3][1]) + (sc[3][2] + sc[3][3]);
                rs = (s0 + s1) + (s2 + s3);
            }
            rs += __shfl_xor(rs, 16, 64);
            rs += __shfl_xor(rs, 32, 64);
            lrow = lrow * corr + rs;
            mrow = mnew;

            // ---- write P (bf16) 4x b64 ----
#pragma unroll
            for (int kc = 0; kc < 4; ++kc) {
                ushort4 pk;
                pk.x = f2bf_fast(sc[kc][0]); pk.y = f2bf_fast(sc[kc][1]);
                pk.z = f2bf_fast(sc[kc][2]); pk.w = f2bf_fast(sc[kc][3]);
                *reinterpret_cast<ushort4*>(Plds + (w * 16 + r16) * 72 + kc * 16 + g4 * 4) = pk;
            }

            // ---- rescale acc ----
            {
                float cr0 = __shfl(corr, g4 * 4 + 0, 64);
                float cr1 = __shfl(corr, g4 * 4 + 1, 64);
                float cr2 = __shfl(corr, g4 * 4 + 2, 64);
                float cr3 = __shfl(corr, g4 * 4 + 3, 64);
#pragma unroll
                for (int f = 0; f < 4; ++f) {
                    f32x4 a = acc[f];
                    a[0] *= cr0; a[1] *= cr1; a[2] *= cr2; a[3] *= cr3;
                    acc[f] = a;
                }
            }

            // ---- PV: O[q][d] += P[q][k] * V[k][d] ----
            __builtin_amdgcn_s_setprio(1);
#pragma unroll
            for (int kc2 = 0; kc2 < 2; ++kc2) {
                bf16x8 pa = *reinterpret_cast<const bf16x8*>(Plds + (w * 16 + r16) * 72 + kc2 * 32 + g4 * 8);
#pragma unroll
                for (int f = 0; f < 4; ++f) {
                    bf16x8 vb = *reinterpret_cast<const bf16x8*>(Vtlds + (f * 16 + r16) * 72 + kc2 * 32 + g4 * 8);
                    acc[f] = __builtin_amdgcn_mfma_f32_16x16x32_bf16(pa, vb, acc[f], 0, 0, 0);
                }
            }
            __builtin_amdgcn_s_setprio(0);
            __syncthreads();

            // ---- store next tile from regs ----
            if (tt + 1 < nt) {
#pragma unroll
                for (int j = 0; j < 2; ++j) {
                    const int rr = j * 32 + krel;
                    *reinterpret_cast<bf16x8*>(Klds + rr * 72 + seg * 8) = kreg[j];
                    *reinterpret_cast<bf16x8*>(Vtlds + rr * 72 + seg * 8) = vreg[j];
                }
                __syncthreads();
            }
        }

        // ---- epilogue: normalize and store ----
        {
            float lr0 = __shfl(lrow, g4 * 4 + 0, 64);
            float lr1 = __shfl(lrow, g4 * 4 + 1, 64);
            float lr2 = __shfl(lrow, g4 * 4 + 2, 64);
            float lr3 = __shfl(lrow, g4 * 4 + 3, 64);
            float lr[4] = {lr0, lr1, lr2, lr3};
#pragma unroll
            for (int f = 0; f < 4; ++f)
#pragma unroll
                for (int r = 0; r < 4; ++r) {
                    int sr = q0 + w * 16 + g4 * 4 + r;
                    float o = acc[f][r] / lr[r];
                    O[bbase + (size_t)sr * 1024 + hoff + f * 16 + r16] = f2bf(o);
                }
        }
    }
}

// ---------------------------------------------------------------------------
extern "C" void kernel_launch(void* const* d_in, const int* in_sizes, int n_in,
                              void* d_out, int out_size, void* d_ws, size_t ws_size,
                              hipStream_t stream) {
    const float* x   = (const float*)d_in[0];
    const int*   sql = (const int*)d_in[1];
    const float* Wq  = (const float*)d_in[2];
    const float* Wk  = (const float*)d_in[3];
    const float* Wv  = (const float*)d_in[4];
    const float* Wo  = (const float*)d_in[5];
    float* out = (float*)d_out;

    const size_t MB = 1024 * 1024;
    char* ws = (char*)d_ws;
    u16* xb   = (u16*)(ws + 0 * MB);
    u16* wqb  = (u16*)(ws + 8 * MB);
    u16* wkb  = (u16*)(ws + 10 * MB);
    u16* wvb  = (u16*)(ws + 12 * MB);
    u16* wob  = (u16*)(ws + 14 * MB);
    u16* Qb   = (u16*)(ws + 16 * MB);
    u16* Kb   = (u16*)(ws + 24 * MB);
    u16* Vtb  = (u16*)(ws + 32 * MB);  // V in transposed layout [bh*64+d][2048]
    u16* attb = (u16*)(ws + 40 * MB);

    // 1) convert inputs to bf16 (Wq pre-scaled by 1/8)
    pma_cvt_kernel<<<4096, 256, 0, stream>>>(x, xb, 1048576);
    pma_cvt4_kernel<<<dim3(1024, 4), 256, 0, stream>>>(Wq, Wk, Wv, Wo, wqb);

    // 2) fused QKV projection; V written transposed (vtr_which = 2)
    pma_gemm_bt<u16><<<dim3(32, 24), 256, 0, stream>>>(xb, wqb, wkb, wvb, Qb, Kb, Vtb, 1024, 8, 2);

    // 3) flash attention: 512 balanced pair-blocks
    pma_attn_kernel<<<512, 256, 0, stream>>>(Qb, Kb, Vtb, sql, attb);

    // 4) output projection -> d_out (fp32)
    pma_gemm_bt<float><<<dim3(32, 8), 256, 0, stream>>>(attb, wob, wob, wob, out, out, out, 1024, 8, -1);
}

// Round 7
// 131.706 us; speedup vs baseline: 1.3898x; 1.0062x over previous
//
#include <hip/hip_runtime.h>

typedef unsigned short u16;
typedef short bf16x8 __attribute__((ext_vector_type(8)));
typedef float f32x4 __attribute__((ext_vector_type(4)));

#define DEVINL __device__ __forceinline__

// fp32 -> bf16 (round-to-nearest-even), bit-level
DEVINL u16 f2bf(float f) {
    union { float f; unsigned int u; } x;
    x.f = f;
    unsigned int u = x.u;
    unsigned int r = (u + 0x7fffu + ((u >> 16) & 1u)) >> 16;
    return (u16)r;
}

// fast fp32 -> bf16 (round-half-up); used for P (bounded, positive) only
DEVINL u16 f2bf_fast(float f) {
    union { float f; unsigned int u; } x;
    x.f = f;
    return (u16)((x.u + 0x8000u) >> 16);
}

// async global->LDS, 16 bytes per lane.
DEVINL void async16(const u16* g, u16* l) {
    __builtin_amdgcn_global_load_lds(
        (const __attribute__((address_space(1))) void*)g,
        (__attribute__((address_space(3))) void*)l, 16, 0, 0);
}

// store helpers: bf16 intermediate vs fp32 final output
DEVINL void store_out(u16* p, float v)   { *p = f2bf(v); }
DEVINL void store_out(float* p, float v) { *p = v; }

// ---------------------------------------------------------------------------
// fp32 -> bf16 convert, vectorized
// ---------------------------------------------------------------------------
__global__ void pma_cvt_kernel(const float* __restrict__ in, u16* __restrict__ out, int n4) {
    int i = blockIdx.x * blockDim.x + threadIdx.x;
    if (i < n4) {
        float4 v = reinterpret_cast<const float4*>(in)[i];
        ushort4 o;
        o.x = f2bf(v.x); o.y = f2bf(v.y); o.z = f2bf(v.z); o.w = f2bf(v.w);
        reinterpret_cast<ushort4*>(out)[i] = o;
    }
}

// 4 weight matrices in one launch; Wq (wsel==0) pre-scaled by 1/8 (= 1/sqrt(64), exact).
__global__ void pma_cvt4_kernel(const float* __restrict__ w0, const float* __restrict__ w1,
                                const float* __restrict__ w2, const float* __restrict__ w3,
                                u16* __restrict__ dst) {
    const int wsel = blockIdx.y;
    const float* in = (wsel == 0) ? w0 : (wsel == 1) ? w1 : (wsel == 2) ? w2 : w3;
    u16* out = dst + (size_t)wsel * 1024 * 1024;
    const float s = (wsel == 0) ? 0.125f : 1.0f;
    int i = blockIdx.x * blockDim.x + threadIdx.x;
    float4 v = reinterpret_cast<const float4*>(in)[i];
    ushort4 o;
    o.x = f2bf(v.x * s); o.y = f2bf(v.y * s); o.z = f2bf(v.z * s); o.w = f2bf(v.w * s);
    reinterpret_cast<ushort4*>(out)[i] = o;
}

// ---------------------------------------------------------------------------
// GEMM: O[m][n] = sum_k A[m][k] * W[n][k], bf16 in, f32 acc, 128x128 tile.
// which == vtr_which (bf16 out only): store transposed into [bh*64+d][2048 s].
// ---------------------------------------------------------------------------
template <typename OutT>
__global__ __launch_bounds__(256) void pma_gemm_bt(
    const u16* __restrict__ A,
    const u16* __restrict__ W0, const u16* __restrict__ W1, const u16* __restrict__ W2,
    OutT* __restrict__ O0, OutT* __restrict__ O1, OutT* __restrict__ O2,
    int K, int nbn_per, int vtr_which)
{
    const int t = threadIdx.x;
    const int lane = t & 63, wave = t >> 6;
    const int m0 = blockIdx.x * 128;
    const int bn = blockIdx.y;
    const int which = bn / nbn_per;
    const int n0 = (bn % nbn_per) * 128;
    const u16* W = (which == 0) ? W0 : (which == 1) ? W1 : W2;
    OutT* O = (which == 0) ? O0 : (which == 1) ? O1 : O2;

    __shared__ u16 Alds[128 * 32];
    __shared__ u16 Blds[128 * 32];

    const int wm = wave >> 1, wn = wave & 1;
    const int r16 = lane & 15, g4 = lane >> 4;

    f32x4 acc[4][4];
    const f32x4 z = {0.f, 0.f, 0.f, 0.f};
#pragma unroll
    for (int m = 0; m < 4; ++m)
#pragma unroll
        for (int n = 0; n < 4; ++n) acc[m][n] = z;

    for (int k0 = 0; k0 < K; k0 += 32) {
        __syncthreads();
#pragma unroll
        for (int j = 0; j < 2; ++j) {
            int i = j * 256 + t;
            int row = i >> 2, seg = i & 3;
            async16(A + (size_t)(m0 + row) * K + k0 + seg * 8,
                    Alds + (size_t)(j * 256 + wave * 64) * 8);
            async16(W + (size_t)(n0 + row) * K + k0 + seg * 8,
                    Blds + (size_t)(j * 256 + wave * 64) * 8);
        }
        __syncthreads();

        bf16x8 af[4], bfr[4];
#pragma unroll
        for (int m = 0; m < 4; ++m)
            af[m] = *reinterpret_cast<const bf16x8*>(Alds + (wm * 64 + m * 16 + r16) * 32 + g4 * 8);
#pragma unroll
        for (int n = 0; n < 4; ++n)
            bfr[n] = *reinterpret_cast<const bf16x8*>(Blds + (wn * 64 + n * 16 + r16) * 32 + g4 * 8);
#pragma unroll
        for (int m = 0; m < 4; ++m)
#pragma unroll
            for (int n = 0; n < 4; ++n)
                acc[m][n] = __builtin_amdgcn_mfma_f32_16x16x32_bf16(af[m], bfr[n], acc[m][n], 0, 0, 0);
    }

    // epilogue: C/D layout col = lane&15, row = (lane>>4)*4 + reg
    bool vtr = false;
    if constexpr (sizeof(OutT) == 2) vtr = (which == vtr_which);
    if (vtr) {
        if constexpr (sizeof(OutT) == 2) {
#pragma unroll
            for (int m = 0; m < 4; ++m)
#pragma unroll
                for (int n = 0; n < 4; ++n) {
                    int row = m0 + wm * 64 + m * 16 + g4 * 4;
                    int col = n0 + wn * 64 + n * 16 + r16;
                    ushort4 pk;
                    pk.x = f2bf(acc[m][n][0]); pk.y = f2bf(acc[m][n][1]);
                    pk.z = f2bf(acc[m][n][2]); pk.w = f2bf(acc[m][n][3]);
                    size_t addr = ((size_t)((row >> 11) * 16 + (col >> 6)) * 64 + (col & 63)) * 2048
                                  + (row & 2047);
                    *reinterpret_cast<ushort4*>((u16*)O + addr) = pk;
                }
        }
    } else {
#pragma unroll
        for (int m = 0; m < 4; ++m)
#pragma unroll
            for (int n = 0; n < 4; ++n) {
                int row = m0 + wm * 64 + m * 16 + g4 * 4;
                int col = n0 + wn * 64 + n * 16 + r16;
#pragma unroll
                for (int r = 0; r < 4; ++r)
                    store_out(&O[(size_t)(row + r) * 1024 + col], acc[m][n][r]);
            }
    }
}

// ---------------------------------------------------------------------------
// Flash attention (causal + padding), bf16 MFMA, fp32 accumulate.
// Grid: 1024 blocks, qt-major (bx = qt*32 + bh) -> co-resident blocks have
// spread qts (balance) and share (b,h) (K/V L2 locality). 4 blocks/CU.
// Swapped QK^T: lane owns q-row r16, 16 keys in-register.
// V pre-transposed in global; T13 defer-rescale (THR=8); exp2-domain softmax.
// ---------------------------------------------------------------------------
__global__ __launch_bounds__(256, 4) void pma_attn_kernel(
    const u16* __restrict__ Q, const u16* __restrict__ Kp, const u16* __restrict__ Vt,
    const int* __restrict__ seq_lengths, u16* __restrict__ O)
{
    const int bx = blockIdx.x;
    const int qt = bx >> 5;          // 32 q-tiles (major)
    const int bh = bx & 31;
    const int h  = bh & 15;
    const int b  = bh >> 4;
    const int q0 = qt * 64;
    const int t = threadIdx.x, lane = t & 63, w = t >> 6;
    const int r16 = lane & 15, g4 = lane >> 4;
    const int seqlen = seq_lengths[b];
    const float L2E = 1.4426950408889634f;

    __shared__ u16 Klds[64 * 72];    // keys x 64d, stride 72
    __shared__ u16 Vtlds[64 * 72];   // d x keys, stride 72
    __shared__ u16 Plds[64 * 72];    // q-rows x keys, stride 72

    const size_t bbase = (size_t)b * 2048 * 1024;
    const size_t hoff = (size_t)h * 64;
    const size_t vrow0 = (size_t)((b * 16 + h) * 64);

    const f32x4 z = {0.f, 0.f, 0.f, 0.f};
    const int krel = t >> 3;         // 0..31
    const int seg  = t & 7;

    const size_t qrowbase = bbase + (size_t)(q0 + w * 16 + r16) * 1024 + hoff;
    const bf16x8 qf0 = *reinterpret_cast<const bf16x8*>(Q + qrowbase + g4 * 8);
    const bf16x8 qf1 = *reinterpret_cast<const bf16x8*>(Q + qrowbase + 32 + g4 * 8);

    f32x4 acc[4];
#pragma unroll
    for (int f = 0; f < 4; ++f) acc[f] = z;
    float mrow = -1e30f, lrow = 0.f;

    int kmax = q0 + 63;
    if (seqlen - 1 < kmax) kmax = seqlen - 1;
    const int nt = (kmax >> 6) + 1;

    // strength-reduced staging bases (row krel, 8-col segment seg)
    const u16* kbase = Kp + bbase + hoff + (size_t)krel * 1024 + seg * 8;
    const u16* vbase = Vt + (vrow0 + krel) * 2048 + seg * 8;

    bf16x8 kreg[2], vreg[2];

    // ---- prologue: load + store tile 0 ----
#pragma unroll
    for (int j = 0; j < 2; ++j) {
        kreg[j] = *reinterpret_cast<const bf16x8*>(kbase + j * 32 * 1024);
        vreg[j] = *reinterpret_cast<const bf16x8*>(vbase + j * 32 * 2048);
    }
#pragma unroll
    for (int j = 0; j < 2; ++j) {
        const int rr = j * 32 + krel;
        *reinterpret_cast<bf16x8*>(Klds + rr * 72 + seg * 8) = kreg[j];
        *reinterpret_cast<bf16x8*>(Vtlds + rr * 72 + seg * 8) = vreg[j];
    }
    __syncthreads();

    const int qhat = q0 + w * 16 + r16;

    for (int tt = 0; tt < nt; ++tt) {
        const int t0 = tt << 6;

        // ---- issue next tile's global loads (hide under compute) ----
        if (tt + 1 < nt) {
            const int t0n = (tt + 1) << 6;
#pragma unroll
            for (int j = 0; j < 2; ++j) {
                kreg[j] = *reinterpret_cast<const bf16x8*>(kbase + (size_t)t0n * 1024 + j * 32 * 1024);
                vreg[j] = *reinterpret_cast<const bf16x8*>(vbase + t0n + j * 32 * 2048);
            }
        }

        // ---- scores (swapped): lane holds 16 keys for q = r16 ----
        f32x4 sraw[4];
        __builtin_amdgcn_s_setprio(1);
#pragma unroll
        for (int kc = 0; kc < 4; ++kc) {
            bf16x8 kf0 = *reinterpret_cast<const bf16x8*>(Klds + (kc * 16 + r16) * 72 + g4 * 8);
            bf16x8 kf1 = *reinterpret_cast<const bf16x8*>(Klds + (kc * 16 + r16) * 72 + 32 + g4 * 8);
            f32x4 s = z;
            s = __builtin_amdgcn_mfma_f32_16x16x32_bf16(kf0, qf0, s, 0, 0, 0);
            s = __builtin_amdgcn_mfma_f32_16x16x32_bf16(kf1, qf1, s, 0, 0, 0);
            sraw[kc] = s;
        }
        __builtin_amdgcn_s_setprio(0);

        float sc[4][4];
        const bool needmask = (t0 == q0) || (t0 + 64 > seqlen);
        if (needmask) {
#pragma unroll
            for (int kc = 0; kc < 4; ++kc) {
                const int keyb = t0 + kc * 16 + g4 * 4;
#pragma unroll
                for (int r = 0; r < 4; ++r)
                    sc[kc][r] = ((keyb + r > qhat) || (keyb + r >= seqlen)) ? -1e30f : sraw[kc][r];
            }
        } else {
#pragma unroll
            for (int kc = 0; kc < 4; ++kc)
#pragma unroll
                for (int r = 0; r < 4; ++r) sc[kc][r] = sraw[kc][r];
        }

        // ---- online softmax (exp2 domain), T13 defer-rescale ----
        float mx;
        {
            float m0 = fmaxf(fmaxf(sc[0][0], sc[0][1]), fmaxf(sc[0][2], sc[0][3]));
            float m1 = fmaxf(fmaxf(sc[1][0], sc[1][1]), fmaxf(sc[1][2], sc[1][3]));
            float m2 = fmaxf(fmaxf(sc[2][0], sc[2][1]), fmaxf(sc[2][2], sc[2][3]));
            float m3 = fmaxf(fmaxf(sc[3][0], sc[3][1]), fmaxf(sc[3][2], sc[3][3]));
            mx = fmaxf(fmaxf(m0, m1), fmaxf(m2, m3));
        }
        mx = fmaxf(mx, __shfl_xor(mx, 16, 64));
        mx = fmaxf(mx, __shfl_xor(mx, 32, 64));

        const bool norescale = __all(mx <= mrow + 8.0f);  // P bounded by e^8
        float mnew, corr;
        if (norescale) { mnew = mrow; corr = 1.0f; }
        else           { mnew = fmaxf(mrow, mx); corr = exp2f((mrow - mnew) * L2E); }

        const float nb = mnew * L2E;
#pragma unroll
        for (int kc = 0; kc < 4; ++kc)
#pragma unroll
            for (int r = 0; r < 4; ++r)
                sc[kc][r] = exp2f(__builtin_fmaf(sc[kc][r], L2E, -nb));
        float rs;
        {
            float s0 = (sc[0][0] + sc[0][1]) + (sc[0][2] + sc[0][3]);
            float s1 = (sc[1][0] + sc[1][1]) + (sc[1][2] + sc[1][3]);
            float s2 = (sc[2][0] + sc[2][1]) + (sc[2][2] + sc[2][3]);
            float s3 = (sc[3][0] + sc[3][1]) + (sc[3][2] + sc[3][3]);
            rs = (s0 + s1) + (s2 + s3);
        }
        rs += __shfl_xor(rs, 16, 64);
        rs += __shfl_xor(rs, 32, 64);
        lrow = lrow * corr + rs;
        mrow = mnew;

        // ---- write P (bf16) 4x b64 ----
#pragma unroll
        for (int kc = 0; kc < 4; ++kc) {
            ushort4 pk;
            pk.x = f2bf_fast(sc[kc][0]); pk.y = f2bf_fast(sc[kc][1]);
            pk.z = f2bf_fast(sc[kc][2]); pk.w = f2bf_fast(sc[kc][3]);
            *reinterpret_cast<ushort4*>(Plds + (w * 16 + r16) * 72 + kc * 16 + g4 * 4) = pk;
        }

        // ---- rescale acc (skipped when max is stable: the common case) ----
        if (!norescale) {
            float cr0 = __shfl(corr, g4 * 4 + 0, 64);
            float cr1 = __shfl(corr, g4 * 4 + 1, 64);
            float cr2 = __shfl(corr, g4 * 4 + 2, 64);
            float cr3 = __shfl(corr, g4 * 4 + 3, 64);
#pragma unroll
            for (int f = 0; f < 4; ++f) {
                f32x4 a = acc[f];
                a[0] *= cr0; a[1] *= cr1; a[2] *= cr2; a[3] *= cr3;
                acc[f] = a;
            }
        }

        // ---- PV: O[q][d] += P[q][k] * V[k][d] ----
        __builtin_amdgcn_s_setprio(1);
#pragma unroll
        for (int kc2 = 0; kc2 < 2; ++kc2) {
            bf16x8 pa = *reinterpret_cast<const bf16x8*>(Plds + (w * 16 + r16) * 72 + kc2 * 32 + g4 * 8);
#pragma unroll
            for (int f = 0; f < 4; ++f) {
                bf16x8 vb = *reinterpret_cast<const bf16x8*>(Vtlds + (f * 16 + r16) * 72 + kc2 * 32 + g4 * 8);
                acc[f] = __builtin_amdgcn_mfma_f32_16x16x32_bf16(pa, vb, acc[f], 0, 0, 0);
            }
        }
        __builtin_amdgcn_s_setprio(0);
        __syncthreads();

        // ---- store next tile from regs ----
        if (tt + 1 < nt) {
#pragma unroll
            for (int j = 0; j < 2; ++j) {
                const int rr = j * 32 + krel;
                *reinterpret_cast<bf16x8*>(Klds + rr * 72 + seg * 8) = kreg[j];
                *reinterpret_cast<bf16x8*>(Vtlds + rr * 72 + seg * 8) = vreg[j];
            }
            __syncthreads();
        }
    }

    // ---- epilogue: normalize and store ----
    {
        float lr0 = __shfl(lrow, g4 * 4 + 0, 64);
        float lr1 = __shfl(lrow, g4 * 4 + 1, 64);
        float lr2 = __shfl(lrow, g4 * 4 + 2, 64);
        float lr3 = __shfl(lrow, g4 * 4 + 3, 64);
        float lr[4] = {lr0, lr1, lr2, lr3};
#pragma unroll
        for (int f = 0; f < 4; ++f)
#pragma unroll
            for (int r = 0; r < 4; ++r) {
                int sr = q0 + w * 16 + g4 * 4 + r;
                float o = acc[f][r] / lr[r];
                O[bbase + (size_t)sr * 1024 + hoff + f * 16 + r16] = f2bf(o);
            }
    }
}

// ---------------------------------------------------------------------------
extern "C" void kernel_launch(void* const* d_in, const int* in_sizes, int n_in,
                              void* d_out, int out_size, void* d_ws, size_t ws_size,
                              hipStream_t stream) {
    const float* x   = (const float*)d_in[0];
    const int*   sql = (const int*)d_in[1];
    const float* Wq  = (const float*)d_in[2];
    const float* Wk  = (const float*)d_in[3];
    const float* Wv  = (const float*)d_in[4];
    const float* Wo  = (const float*)d_in[5];
    float* out = (float*)d_out;

    const size_t MB = 1024 * 1024;
    char* ws = (char*)d_ws;
    u16* xb   = (u16*)(ws + 0 * MB);
    u16* wqb  = (u16*)(ws + 8 * MB);
    u16* wkb  = (u16*)(ws + 10 * MB);
    u16* wvb  = (u16*)(ws + 12 * MB);
    u16* wob  = (u16*)(ws + 14 * MB);
    u16* Qb   = (u16*)(ws + 16 * MB);
    u16* Kb   = (u16*)(ws + 24 * MB);
    u16* Vtb  = (u16*)(ws + 32 * MB);  // V transposed layout [bh*64+d][2048]
    u16* attb = (u16*)(ws + 40 * MB);

    // 1) convert inputs to bf16 (Wq pre-scaled by 1/8)
    pma_cvt_kernel<<<4096, 256, 0, stream>>>(x, xb, 1048576);
    pma_cvt4_kernel<<<dim3(1024, 4), 256, 0, stream>>>(Wq, Wk, Wv, Wo, wqb);

    // 2) fused QKV projection; V written transposed (vtr_which = 2)
    pma_gemm_bt<u16><<<dim3(32, 24), 256, 0, stream>>>(xb, wqb, wkb, wvb, Qb, Kb, Vtb, 1024, 8, 2);

    // 3) flash attention: 1024 blocks, qt-major (4 blocks/CU, 16 waves/CU)
    pma_attn_kernel<<<1024, 256, 0, stream>>>(Qb, Kb, Vtb, sql, attb);

    // 4) output projection -> d_out (fp32)
    pma_gemm_bt<float><<<dim3(32, 8), 256, 0, stream>>>(attb, wob, wob, wob, out, out, out, 1024, 8, -1);
}